// Round 8
// baseline (181.153 us; speedup 1.0000x reference)
//
#include <hip/hip_runtime.h>
#include <math.h>

// Tropical min-max matmul: out[b,o] = min_i max(x[b,i], w[i,o])
// B=1024, I=512, O=512, fp32.
//
// Round 8: fused split-K with "last block combines" tail. No per-element
// atomics (R7: 8.4M atomicMin -> 134MB HBM write-through, 128us). No
// separate reduce kernel (R2-R5: cross-XCD partial reads ~15-20us).
//  - Core: R7's 128x128 tile, 8x8/thread, K=32/block staged once
//    (SQ_LDS_BANK_CONFLICT measured 0). Grid 512 = 2 blocks/CU.
//  - Each block: write 64KB partial to d_ws, __threadfence (release),
//    atomicAdd(cnt[tile]) -- 32 counters, 512 atomics total. Block seeing
//    old==15 acquires and min-combines its tile's 16 partials (1MB read,
//    32 combiner blocks in parallel) -> d_out. Deadlock-free under any
//    dispatch/occupancy; no co-residency assumption (rigor: G16).
//  - id mapping: tile8 = id&7 so a tile's 16 z-blocks share an XCD under
//    round-robin dispatch (and split across only 2 XCDs if chunked) ->
//    combine reads are L2-local. Speed heuristic only.
//  - Counters zeroed by 128B hipMemsetAsync each call (graph-safe).
//  - VALU floor: 512M updates * 1.5 ops / 78.6 T/s = 9.8us; LDS pipe
//    ~9.8us; expect ~16-22us incl. staging + combine tail.

#define XS_STRIDE 36

__device__ __forceinline__ float4 vmax4(float s, float4 v) {
    return make_float4(fmaxf(s, v.x), fmaxf(s, v.y), fmaxf(s, v.z), fmaxf(s, v.w));
}
__device__ __forceinline__ float4 vmin3(float4 a, float4 b, float4 c) {
    // fmin(fmin(a,b),c) -> v_min3_f32
    return make_float4(fminf(fminf(a.x, b.x), c.x),
                       fminf(fminf(a.y, b.y), c.y),
                       fminf(fminf(a.z, b.z), c.z),
                       fminf(fminf(a.w, b.w), c.w));
}
__device__ __forceinline__ float4 vmin2(float4 a, float4 b) {
    return make_float4(fminf(a.x, b.x), fminf(a.y, b.y),
                       fminf(a.z, b.z), fminf(a.w, b.w));
}

__global__ __launch_bounds__(256, 2) void minmax_fused(
    const float* __restrict__ x,    // [1024, 512]
    const float* __restrict__ w,    // [512, 512]
    float* __restrict__ out,        // [1024, 512]
    float* __restrict__ part,       // [32 tiles][16 z][128][128] = 32 MB
    unsigned int* __restrict__ cnt) // [32], zeroed before launch
{
    __shared__ float xs[128 * XS_STRIDE];   // 18432 B
    __shared__ float wsh[32 * 128];         // 16384 B
    __shared__ unsigned int sOld;

    const int id   = blockIdx.x;                    // 0..511
    const int tile = ((id >> 7) << 3) | (id & 7);   // 0..31 (id&7 -> XCD-stable)
    const int z    = (id >> 3) & 15;                // 0..15 k-slice
    const int o0   = (tile & 3) * 128;
    const int b0   = (tile >> 2) * 128;
    const int kb   = z * 32;

    const int t  = threadIdx.x;
    const int tx = t & 15;          // cols tx*4..+3 and 64+tx*4..+3
    const int ty = t >> 4;          // rows ty+16r, r=0..7

    // ---- stage both tiles (K=32 slab), coalesced b128, conflict-free ----
#pragma unroll
    for (int i = 0; i < 4; ++i) {
        const int f = i * 256 + t;
        const int row = f >> 3, c4 = (f & 7) * 4;
        *(float4*)(xs + row * XS_STRIDE + c4) =
            *(const float4*)(x + (size_t)(b0 + row) * 512 + kb + c4);
    }
#pragma unroll
    for (int i = 0; i < 4; ++i) {
        const int f = i * 256 + t;
        const int k = f >> 5, c4 = (f & 31) * 4;
        *(float4*)(wsh + k * 128 + c4) =
            *(const float4*)(w + (size_t)(kb + k) * 512 + o0 + c4);
    }
    __syncthreads();

    float4 acc[8][2];
#pragma unroll
    for (int r = 0; r < 8; ++r)
#pragma unroll
        for (int g = 0; g < 2; ++g)
            acc[r][g] = make_float4(INFINITY, INFINITY, INFINITY, INFINITY);

#pragma unroll
    for (int k4 = 0; k4 < 8; ++k4) {
        float4 xf[8];
#pragma unroll
        for (int r = 0; r < 8; ++r)
            xf[r] = *(const float4*)(xs + (ty + 16 * r) * XS_STRIDE + 4 * k4);
        float4 wf[4][2];
#pragma unroll
        for (int j = 0; j < 4; ++j)
#pragma unroll
            for (int g = 0; g < 2; ++g)
                wf[j][g] = *(const float4*)(wsh + (4 * k4 + j) * 128 + tx * 4 + 64 * g);
#pragma unroll
        for (int r = 0; r < 8; ++r) {
#pragma unroll
            for (int g = 0; g < 2; ++g) {
                float4 a = acc[r][g];
                a = vmin3(a, vmax4(xf[r].x, wf[0][g]), vmax4(xf[r].y, wf[1][g]));
                a = vmin3(a, vmax4(xf[r].z, wf[2][g]), vmax4(xf[r].w, wf[3][g]));
                acc[r][g] = a;
            }
        }
    }

    // ---- write this block's 64KB partial slice ----
    float* pt = part + ((size_t)tile * 16 + z) * 16384;
#pragma unroll
    for (int r = 0; r < 8; ++r)
#pragma unroll
        for (int g = 0; g < 2; ++g)
            *(float4*)(pt + (ty + 16 * r) * 128 + tx * 4 + 64 * g) = acc[r][g];

    // ---- release + arrive ----
    __threadfence();                 // each thread releases its own stores
    __syncthreads();                 // all fences ordered before the add
    if (t == 0) sOld = atomicAdd(&cnt[tile], 1u);
    __syncthreads();
    if (sOld != 15u) return;         // not last: done
    __threadfence();                 // acquire side of the counter chain

    // ---- last block of this tile: combine 16 partials -> out ----
    const float4* pp = (const float4*)(part + (size_t)tile * 16 * 16384);
    float4* outv = (float4*)out;
    const int ocol4 = o0 >> 2;
#pragma unroll 4
    for (int i = 0; i < 16; ++i) {
        const int c = t + 256 * i;           // float4 cell 0..4095
        float4 v = pp[c];
#pragma unroll
        for (int zz = 1; zz < 16; ++zz)
            v = vmin2(v, pp[c + zz * 4096]);
        const int row = c >> 5, cc = c & 31;
        outv[(size_t)(b0 + row) * 128 + ocol4 + cc] = v;
    }
}

// fallback (ws too small): direct, no split-K, 32 blocks, correct but slow
__global__ __launch_bounds__(256) void minmax_direct(
    const float* __restrict__ x, const float* __restrict__ w,
    float* __restrict__ out)
{
    __shared__ float xs[128 * XS_STRIDE];
    __shared__ float wsh[32 * 128];
    const int t = threadIdx.x, tx = t & 15, ty = t >> 4;
    const int o0 = blockIdx.x * 128, b0 = blockIdx.y * 128;
    float4 acc[8][2];
#pragma unroll
    for (int r = 0; r < 8; ++r)
#pragma unroll
        for (int g = 0; g < 2; ++g)
            acc[r][g] = make_float4(INFINITY, INFINITY, INFINITY, INFINITY);
    for (int s = 0; s < 16; ++s) {
        const int kb = s * 32;
        __syncthreads();
#pragma unroll
        for (int i = 0; i < 4; ++i) {
            const int f = i * 256 + t;
            const int row = f >> 3, c4 = (f & 7) * 4;
            *(float4*)(xs + row * XS_STRIDE + c4) =
                *(const float4*)(x + (size_t)(b0 + row) * 512 + kb + c4);
        }
#pragma unroll
        for (int i = 0; i < 4; ++i) {
            const int f = i * 256 + t;
            const int k = f >> 5, c4 = (f & 31) * 4;
            *(float4*)(wsh + k * 128 + c4) =
                *(const float4*)(w + (size_t)(kb + k) * 512 + o0 + c4);
        }
        __syncthreads();
#pragma unroll
        for (int k4 = 0; k4 < 8; ++k4) {
            float4 xf[8];
#pragma unroll
            for (int r = 0; r < 8; ++r)
                xf[r] = *(const float4*)(xs + (ty + 16 * r) * XS_STRIDE + 4 * k4);
            float4 wf[4][2];
#pragma unroll
            for (int j = 0; j < 4; ++j)
#pragma unroll
                for (int g = 0; g < 2; ++g)
                    wf[j][g] = *(const float4*)(wsh + (4 * k4 + j) * 128 + tx * 4 + 64 * g);
#pragma unroll
            for (int r = 0; r < 8; ++r)
#pragma unroll
                for (int g = 0; g < 2; ++g) {
                    float4 a = acc[r][g];
                    a = vmin3(a, vmax4(xf[r].x, wf[0][g]), vmax4(xf[r].y, wf[1][g]));
                    a = vmin3(a, vmax4(xf[r].z, wf[2][g]), vmax4(xf[r].w, wf[3][g]));
                    acc[r][g] = a;
                }
        }
    }
#pragma unroll
    for (int r = 0; r < 8; ++r)
#pragma unroll
        for (int g = 0; g < 2; ++g)
            *(float4*)(out + (size_t)(b0 + ty + 16 * r) * 512 + o0 + tx * 4 + 64 * g) = acc[r][g];
}

extern "C" void kernel_launch(void* const* d_in, const int* in_sizes, int n_in,
                              void* d_out, int out_size, void* d_ws, size_t ws_size,
                              hipStream_t stream) {
    const float* x = (const float*)d_in[0];   // [1024, 512]
    const float* w = (const float*)d_in[1];   // [512, 512]
    float* out = (float*)d_out;               // [1024, 512]

    const size_t part_bytes = 32ull * 1024 * 1024;    // 32 tiles * 16 z * 64KB
    if (ws_size >= part_bytes + 128) {
        float* part = (float*)d_ws;
        unsigned int* cnt = (unsigned int*)((char*)d_ws + part_bytes);
        hipMemsetAsync(cnt, 0, 128, stream);          // zero 32 tile counters
        minmax_fused<<<dim3(512), 256, 0, stream>>>(x, w, out, part, cnt);
    } else {
        minmax_direct<<<dim3(4, 8), 256, 0, stream>>>(x, w, out);
    }
}

// Round 9
// 83.656 us; speedup vs baseline: 2.1654x; 2.1654x over previous
//
#include <hip/hip_runtime.h>
#include <math.h>

// Tropical min-max matmul: out[b,o] = min_i max(x[b,i], w[i,o])
// B=1024, I=512, O=512, fp32.
//
// Round 9: two plain kernels (no atomics, no fences — R7/R8 showed any
// cross-XCD handoff inside a kernel costs >=100us on non-coherent L2s).
//  - part: 128x128 tile, 8x8/thread (measured conflict-free, LDS:VALU 1:1
//    = 5.1us:5.1us per CU), 512-thread blocks = two 256-thread groups
//    splitting K=64 intra-block (combine via LDS, one extra barrier).
//    Grid 256 = 1 block/CU = 8 waves/CU = 2 waves/SIMD. Global split-K=8
//    -> 16MB partials (half of R4).
//  - XCD locality: producer id = z*32 + tile => XCD=id%8=tile%8 under
//    round-robin; a tile's 8 partials (512KB) stay in one XCD's L2
//    (2MB/XCD). reduce maps tile=id%32 -> same XCD -> L2-local reads.
//  - LDS: single 69632B union: staging xs[128][68] + ws[64][128] (67584B),
//    then reused as the 256x68-float combine buffer. All accesses audited
//    2-way-or-less (free per m136).

__device__ __forceinline__ float4 vmax4(float s, float4 v) {
    return make_float4(fmaxf(s, v.x), fmaxf(s, v.y), fmaxf(s, v.z), fmaxf(s, v.w));
}
__device__ __forceinline__ float4 vmin3(float4 a, float4 b, float4 c) {
    return make_float4(fminf(fminf(a.x, b.x), c.x),
                       fminf(fminf(a.y, b.y), c.y),
                       fminf(fminf(a.z, b.z), c.z),
                       fminf(fminf(a.w, b.w), c.w));
}
__device__ __forceinline__ float4 vmin2(float4 a, float4 b) {
    return make_float4(fminf(a.x, b.x), fminf(a.y, b.y),
                       fminf(a.z, b.z), fminf(a.w, b.w));
}

__global__ __launch_bounds__(512, 2) void minmax_part(
    const float* __restrict__ x,    // [1024, 512]
    const float* __restrict__ w,    // [512, 512]
    float* __restrict__ part)       // [32 tiles][8 z][128][128] = 16 MB
{
    __shared__ float lds[17408];    // 69632 B union
    float* xs  = lds;               // [128][68] staging (stride 68 = 17 quads)
    float* wsh = lds + 8704;        // [64][128] staging

    const int t    = threadIdx.x;   // 0..511
    const int id   = blockIdx.x;    // 0..255
    const int tile = id & 31;       // XCD = id%8 = tile%8 (round-robin)
    const int z    = id >> 5;       // 0..7
    const int o0   = (tile & 3) * 128;
    const int b0   = (tile >> 2) * 128;
    const int kb   = z * 64;

    const int g  = t >> 8;          // k-group 0/1
    const int t2 = t & 255;
    const int tx = t2 & 15;         // cols tx*4..+3 and 64+tx*4..+3
    const int ty = t2 >> 4;         // rows ty+16r, r=0..7

    // ---- stage x[128][64] and w[64][128] once, all 512 threads ----
#pragma unroll
    for (int i = 0; i < 4; ++i) {
        const int f = i * 512 + t;              // 0..2047
        const int row = f >> 4, c4 = (f & 15) * 4;
        *(float4*)(xs + row * 68 + c4) =
            *(const float4*)(x + (size_t)(b0 + row) * 512 + kb + c4);
    }
#pragma unroll
    for (int i = 0; i < 4; ++i) {
        const int f = i * 512 + t;
        const int k = f >> 5, c4 = (f & 31) * 4;
        *(float4*)(wsh + k * 128 + c4) =
            *(const float4*)(w + (size_t)(kb + k) * 512 + o0 + c4);
    }
    __syncthreads();

    float4 acc[8][2];
#pragma unroll
    for (int r = 0; r < 8; ++r)
#pragma unroll
        for (int q = 0; q < 2; ++q)
            acc[r][q] = make_float4(INFINITY, INFINITY, INFINITY, INFINITY);

    const float* xg = xs + g * 32;          // this group's k-offset
    const float* wg = wsh + g * 32 * 128;

#pragma unroll
    for (int k4 = 0; k4 < 8; ++k4) {
        float4 xf[8];
#pragma unroll
        for (int r = 0; r < 8; ++r)
            xf[r] = *(const float4*)(xg + (ty + 16 * r) * 68 + 4 * k4);
        float4 wf[4][2];
#pragma unroll
        for (int j = 0; j < 4; ++j)
#pragma unroll
            for (int q = 0; q < 2; ++q)
                wf[j][q] = *(const float4*)(wg + (4 * k4 + j) * 128 + tx * 4 + 64 * q);
#pragma unroll
        for (int r = 0; r < 8; ++r) {
#pragma unroll
            for (int q = 0; q < 2; ++q) {
                float4 a = acc[r][q];
                a = vmin3(a, vmax4(xf[r].x, wf[0][q]), vmax4(xf[r].y, wf[1][q]));
                a = vmin3(a, vmax4(xf[r].z, wf[2][q]), vmax4(xf[r].w, wf[3][q]));
                acc[r][q] = a;
            }
        }
    }

    // ---- intra-block combine: group 1 -> LDS, group 0 mins & stores ----
    __syncthreads();                 // staging reads done; safe to reuse lds
    if (g == 1) {
        float* s = lds + t2 * 68;    // stride 17 quads -> 2-way max (free)
#pragma unroll
        for (int r = 0; r < 8; ++r)
#pragma unroll
            for (int q = 0; q < 2; ++q)
                *(float4*)(s + (r * 2 + q) * 4) = acc[r][q];
    }
    __syncthreads();
    if (g == 0) {
        const float* s = lds + t2 * 68;
        float* pt = part + ((size_t)tile * 8 + z) * 16384;
#pragma unroll
        for (int r = 0; r < 8; ++r)
#pragma unroll
            for (int q = 0; q < 2; ++q) {
                const float4 o = vmin2(acc[r][q], *(const float4*)(s + (r * 2 + q) * 4));
                *(float4*)(pt + (ty + 16 * r) * 128 + tx * 4 + 64 * q) = o;
            }
    }
}

// grid 128: tile = id%32 (same XCD as producers), quarter = id/32.
__global__ __launch_bounds__(256) void minmax_reduce(
    const float4* __restrict__ part, float4* __restrict__ out)
{
    const int t    = threadIdx.x;
    const int id   = blockIdx.x;
    const int tile = id & 31;
    const int qt   = id >> 5;            // 0..3
    const int oc4  = (tile & 3) * 32;    // f4 col offset
    const int b0   = (tile >> 2) * 128;

    const float4* pp = part + (size_t)tile * 8 * 4096;
#pragma unroll
    for (int i = 0; i < 4; ++i) {
        const int c = qt * 1024 + i * 256 + t;   // f4 cell 0..4095
        float4 v = pp[c];
#pragma unroll
        for (int z = 1; z < 8; ++z)
            v = vmin2(v, pp[z * 4096 + c]);
        const int row = c >> 5, cc = c & 31;
        out[(size_t)(b0 + row) * 128 + oc4 + cc] = v;
    }
}

// fallback (ws too small): direct, no split-K, correct but low occupancy
__global__ __launch_bounds__(256) void minmax_direct(
    const float* __restrict__ x, const float* __restrict__ w,
    float* __restrict__ out)
{
    __shared__ float xs[128 * 36];
    __shared__ float wsh[32 * 128];
    const int t = threadIdx.x, tx = t & 15, ty = t >> 4;
    const int o0 = blockIdx.x * 128, b0 = blockIdx.y * 128;
    float4 acc[8][2];
#pragma unroll
    for (int r = 0; r < 8; ++r)
#pragma unroll
        for (int q = 0; q < 2; ++q)
            acc[r][q] = make_float4(INFINITY, INFINITY, INFINITY, INFINITY);
    for (int s = 0; s < 16; ++s) {
        const int kb = s * 32;
        __syncthreads();
#pragma unroll
        for (int i = 0; i < 4; ++i) {
            const int f = i * 256 + t;
            const int row = f >> 3, c4 = (f & 7) * 4;
            *(float4*)(xs + row * 36 + c4) =
                *(const float4*)(x + (size_t)(b0 + row) * 512 + kb + c4);
        }
#pragma unroll
        for (int i = 0; i < 4; ++i) {
            const int f = i * 256 + t;
            const int k = f >> 5, c4 = (f & 31) * 4;
            *(float4*)(wsh + k * 128 + c4) =
                *(const float4*)(w + (size_t)(kb + k) * 512 + o0 + c4);
        }
        __syncthreads();
#pragma unroll
        for (int k4 = 0; k4 < 8; ++k4) {
            float4 xf[8];
#pragma unroll
            for (int r = 0; r < 8; ++r)
                xf[r] = *(const float4*)(xs + (ty + 16 * r) * 36 + 4 * k4);
            float4 wf[4][2];
#pragma unroll
            for (int j = 0; j < 4; ++j)
#pragma unroll
                for (int q = 0; q < 2; ++q)
                    wf[j][q] = *(const float4*)(wsh + (4 * k4 + j) * 128 + tx * 4 + 64 * q);
#pragma unroll
            for (int r = 0; r < 8; ++r)
#pragma unroll
                for (int q = 0; q < 2; ++q) {
                    float4 a = acc[r][q];
                    a = vmin3(a, vmax4(xf[r].x, wf[0][q]), vmax4(xf[r].y, wf[1][q]));
                    a = vmin3(a, vmax4(xf[r].z, wf[2][q]), vmax4(xf[r].w, wf[3][q]));
                    acc[r][q] = a;
                }
        }
    }
#pragma unroll
    for (int r = 0; r < 8; ++r)
#pragma unroll
        for (int q = 0; q < 2; ++q)
            *(float4*)(out + (size_t)(b0 + ty + 16 * r) * 512 + o0 + tx * 4 + 64 * q) = acc[r][q];
}

extern "C" void kernel_launch(void* const* d_in, const int* in_sizes, int n_in,
                              void* d_out, int out_size, void* d_ws, size_t ws_size,
                              hipStream_t stream) {
    const float* x = (const float*)d_in[0];   // [1024, 512]
    const float* w = (const float*)d_in[1];   // [512, 512]
    float* out = (float*)d_out;               // [1024, 512]

    const size_t part_bytes = 16ull * 1024 * 1024;   // 32 tiles * 8 z * 64KB
    if (ws_size >= part_bytes) {
        float* part = (float*)d_ws;
        minmax_part<<<dim3(256), 512, 0, stream>>>(x, w, part);
        minmax_reduce<<<dim3(128), 256, 0, stream>>>((const float4*)part, (float4*)out);
    } else {
        minmax_direct<<<dim3(4, 8), 256, 0, stream>>>(x, w, out);
    }
}